// Round 1
// baseline (535.274 us; speedup 1.0000x reference)
//
#include <hip/hip_runtime.h>

// MultiHeadAttention: B=4, S=2048, D=1024, H=16, depth=64.
// Pipeline: cvt(fp32->bf16) -> QKV GEMM (bf16 MFMA) -> flash attention -> out GEMM.
// Workspace layout (bytes):
//   [0,16M)   qb  (bf16 q)          -- reused as ctx after projections
//   [16,32M)  kb  [32,48M) vb
//   [48,56M)  Wq/Wk/Wv/Wo transposed bf16 (2MB each)
//   [56,72M)  Qh [B,H,S,64]  [72,88M) Kh [B,H,S,64]  [88,104M) Vht [B,H,64,S]
// Total ws need: 104 MB.

typedef unsigned short ushort_t;
typedef __bf16          b16x8 __attribute__((ext_vector_type(8)));
typedef unsigned short  u16x8 __attribute__((ext_vector_type(8)));
typedef unsigned short  u16x4 __attribute__((ext_vector_type(4)));
typedef float           f32x4 __attribute__((ext_vector_type(4)));

#define B_ 4
#define S_ 2048
#define D_ 1024
#define H_ 16
#define DEPTH_ 64

__device__ __forceinline__ unsigned short f2bf(float f) {
  unsigned u = __builtin_bit_cast(unsigned, f);
  u += 0x7FFFu + ((u >> 16) & 1u);   // RTNE
  return (unsigned short)(u >> 16);
}

#define GLD16(gp, lp) __builtin_amdgcn_global_load_lds( \
    (__attribute__((address_space(1))) void*)(gp),       \
    (__attribute__((address_space(3))) void*)(lp), 16, 0, 0)

#define MFMA_BF16(a, b, c) __builtin_amdgcn_mfma_f32_16x16x32_bf16( \
    __builtin_bit_cast(b16x8, (a)), __builtin_bit_cast(b16x8, (b)), (c), 0, 0, 0)

// ---------------- converts ----------------

__global__ void cvt_acts_kernel(const float* __restrict__ q, const float* __restrict__ k,
                                const float* __restrict__ v,
                                ushort_t* __restrict__ qb, ushort_t* __restrict__ kb,
                                ushort_t* __restrict__ vb) {
  const float* src = blockIdx.y == 0 ? q : blockIdx.y == 1 ? k : v;
  ushort_t*    dst = blockIdx.y == 0 ? qb : blockIdx.y == 1 ? kb : vb;
  size_t i = ((size_t)blockIdx.x * 256 + threadIdx.x) * 4;
  float4 f = *(const float4*)(src + i);
  u16x4 o;
  o[0] = f2bf(f.x); o[1] = f2bf(f.y); o[2] = f2bf(f.z); o[3] = f2bf(f.w);
  *(u16x4*)(dst + i) = o;
}

// W [K=1024][N=1024] fp32 -> Wt [N][K] bf16 (tiled transpose)
__global__ void cvt_wt_kernel(const float* __restrict__ Wq, const float* __restrict__ Wk,
                              const float* __restrict__ Wv, const float* __restrict__ Wo,
                              ushort_t* __restrict__ Wqt, ushort_t* __restrict__ Wkt,
                              ushort_t* __restrict__ Wvt, ushort_t* __restrict__ Wot) {
  __shared__ float t[32][33];
  const int z = blockIdx.y;
  const float* W = z == 0 ? Wq : z == 1 ? Wk : z == 2 ? Wv : Wo;
  ushort_t*   Wt = z == 0 ? Wqt : z == 1 ? Wkt : z == 2 ? Wvt : Wot;
  const int x = threadIdx.x & 31, y0 = threadIdx.x >> 5;
  const int kt = (blockIdx.x & 31) * 32, nt = (blockIdx.x >> 5) * 32;
#pragma unroll
  for (int r = 0; r < 4; r++) {
    int row = y0 + r * 8;
    t[row][x] = W[(size_t)(kt + row) * D_ + nt + x];
  }
  __syncthreads();
#pragma unroll
  for (int r = 0; r < 4; r++) {
    int row = y0 + r * 8;
    Wt[(size_t)(nt + row) * D_ + kt + x] = f2bf(t[x][row]);
  }
}

// ---------------- GEMM core (m97 pattern: 128x128 tile, BK=32, global_load_lds) ----------------
// A [M][1024] bf16 row-major, Bt [N][1024] bf16 row-major (i.e. B^T). acc[mi*4+ni].

__device__ __forceinline__ void gemm_core(const ushort_t* __restrict__ A,
                                          const ushort_t* __restrict__ Bt,
                                          ushort_t* As, ushort_t* Bs,
                                          int tm, int tn, f32x4* acc) {
  const int tid = threadIdx.x;
  const int lane = tid & 63, wid = tid >> 6;
  const int wm = (wid >> 1) * 64, wn = (wid & 1) * 64;
  const int srow = lane >> 2, scol = (lane & 3) * 8;
  const int c0 = wid * 2, c1 = c0 + 1;
  const ushort_t* ga0 = A  + (size_t)(tm + c0 * 16 + srow) * D_ + scol;
  const ushort_t* ga1 = A  + (size_t)(tm + c1 * 16 + srow) * D_ + scol;
  const ushort_t* gb0 = Bt + (size_t)(tn + c0 * 16 + srow) * D_ + scol;
  const ushort_t* gb1 = Bt + (size_t)(tn + c1 * 16 + srow) * D_ + scol;
  ushort_t* lA0 = As + c0 * 512; ushort_t* lA1 = As + c1 * 512;
  ushort_t* lB0 = Bs + c0 * 512; ushort_t* lB1 = Bs + c1 * 512;
  const int fr = lane & 15, fq = (lane >> 4) * 8;
#pragma unroll
  for (int i = 0; i < 16; i++) acc[i] = f32x4{0.f, 0.f, 0.f, 0.f};
  for (int k0 = 0; k0 < D_; k0 += 32) {
    __syncthreads();
    GLD16(ga0 + k0, lA0);
    GLD16(ga1 + k0, lA1);
    GLD16(gb0 + k0, lB0);
    GLD16(gb1 + k0, lB1);
    __syncthreads();
    u16x8 af[4], bf[4];
#pragma unroll
    for (int mi = 0; mi < 4; mi++) af[mi] = *(const u16x8*)(As + (wm + mi * 16 + fr) * 32 + fq);
#pragma unroll
    for (int ni = 0; ni < 4; ni++) bf[ni] = *(const u16x8*)(Bs + (wn + ni * 16 + fr) * 32 + fq);
#pragma unroll
    for (int mi = 0; mi < 4; mi++)
#pragma unroll
      for (int ni = 0; ni < 4; ni++)
        acc[mi * 4 + ni] = MFMA_BF16(af[mi], bf[ni], acc[mi * 4 + ni]);
  }
}

// z=0: Q -> Qh [B,H,S,64]; z=1: K -> Kh [B,H,S,64]; z=2: V -> Vht [B,H,64,S]
__global__ __launch_bounds__(256, 2) void qkv_gemm_kernel(
    const ushort_t* __restrict__ qb, const ushort_t* __restrict__ kb, const ushort_t* __restrict__ vb,
    const ushort_t* __restrict__ Wqt, const ushort_t* __restrict__ Wkt, const ushort_t* __restrict__ Wvt,
    const float* __restrict__ bq, const float* __restrict__ bk, const float* __restrict__ bv,
    ushort_t* __restrict__ Qh, ushort_t* __restrict__ Kh, ushort_t* __restrict__ Vht) {
  __shared__ __align__(16) ushort_t As[4096], Bs[4096];
  const int z = blockIdx.z;
  const ushort_t* A  = z == 0 ? qb : z == 1 ? kb : vb;
  const ushort_t* Bt = z == 0 ? Wqt : z == 1 ? Wkt : Wvt;
  const float* bias  = z == 0 ? bq : z == 1 ? bk : bv;
  ushort_t* outp     = z == 0 ? Qh : z == 1 ? Kh : Vht;
  const int tn = blockIdx.x * 128, tm = blockIdx.y * 128;
  f32x4 acc[16];
  gemm_core(A, Bt, As, Bs, tm, tn, acc);
  const int lane = threadIdx.x & 63, wid = threadIdx.x >> 6;
  const int wm = (wid >> 1) * 64, wn = (wid & 1) * 64;
  const int fr = lane & 15, rq = (lane >> 4) * 4;
#pragma unroll
  for (int ni = 0; ni < 4; ni++) {
    const int col = tn + wn + ni * 16 + fr;
    const float bb = bias[col];
    const int h = col >> 6, dd = col & 63;
#pragma unroll
    for (int mi = 0; mi < 4; mi++) {
#pragma unroll
      for (int r = 0; r < 4; r++) {
        const int m = tm + wm + mi * 16 + rq + r;
        const int b = m >> 11, s = m & 2047;
        const unsigned short val = f2bf(acc[mi * 4 + ni][r] + bb);
        if (z < 2)
          outp[((size_t)(b * H_ + h) * S_ + s) * DEPTH_ + dd] = val;
        else
          outp[((size_t)(b * H_ + h) * DEPTH_ + dd) * S_ + s] = val;
      }
    }
  }
}

__global__ __launch_bounds__(256, 2) void out_gemm_kernel(
    const ushort_t* __restrict__ ctx, const ushort_t* __restrict__ Wot,
    const float* __restrict__ bo, float* __restrict__ out) {
  __shared__ __align__(16) ushort_t As[4096], Bs[4096];
  const int tn = blockIdx.x * 128, tm = blockIdx.y * 128;
  f32x4 acc[16];
  gemm_core(ctx, Wot, As, Bs, tm, tn, acc);
  const int lane = threadIdx.x & 63, wid = threadIdx.x >> 6;
  const int wm = (wid >> 1) * 64, wn = (wid & 1) * 64;
  const int fr = lane & 15, rq = (lane >> 4) * 4;
#pragma unroll
  for (int ni = 0; ni < 4; ni++) {
    const int col = tn + wn + ni * 16 + fr;
    const float bb = bo[col];
#pragma unroll
    for (int mi = 0; mi < 4; mi++) {
#pragma unroll
      for (int r = 0; r < 4; r++) {
        const int m = tm + wm + mi * 16 + rq + r;
        out[(size_t)m * D_ + col] = acc[mi * 4 + ni][r] + bb;
      }
    }
  }
}

// ---------------- flash attention ----------------
// grid (16 q-tiles, 64 bh). 4 waves x 32 q-rows. K/V tiles of 128 keys.

__global__ __launch_bounds__(256, 2) void attn_kernel(
    const ushort_t* __restrict__ Qh, const ushort_t* __restrict__ Kh,
    const ushort_t* __restrict__ Vht, const int* __restrict__ mask,
    ushort_t* __restrict__ ctx) {
  __shared__ __align__(16) ushort_t Ks[128 * 64];   // [key][d]
  __shared__ __align__(16) ushort_t Vs[64 * 128];   // [d][key] (from Vht)
  __shared__ __align__(16) ushort_t Ps[4 * 32 * 128];
  const int tid = threadIdx.x, lane = tid & 63, wid = tid >> 6;
  const int qt = blockIdx.x, bh = blockIdx.y;
  const int b = bh >> 4, h = bh & 15;
  const size_t base = (size_t)bh * (S_ * DEPTH_);
  const int fr = lane & 15, fq = lane >> 4;

  // Q fragments for this wave's 32 rows, scaled by 1/sqrt(64)=0.125 (exact in bf16)
  u16x8 qf[2][2];
#pragma unroll
  for (int mi = 0; mi < 2; mi++)
#pragma unroll
    for (int ks = 0; ks < 2; ks++) {
      const ushort_t* p = Qh + base + (size_t)(qt * 128 + wid * 32 + mi * 16 + fr) * DEPTH_ + ks * 32 + fq * 8;
      u16x8 t = *(const u16x8*)p;
#pragma unroll
      for (int j = 0; j < 8; j++) {
        float f = __builtin_bit_cast(float, ((unsigned)t[j]) << 16) * 0.125f;
        qf[mi][ks][j] = (unsigned short)(__builtin_bit_cast(unsigned, f) >> 16);
      }
    }

  float mstate[2][4], lstate[2][4];
  f32x4 O[2][4];
#pragma unroll
  for (int mi = 0; mi < 2; mi++) {
#pragma unroll
    for (int r = 0; r < 4; r++) { mstate[mi][r] = -1e30f; lstate[mi][r] = 0.f; }
#pragma unroll
    for (int di = 0; di < 4; di++) O[mi][di] = f32x4{0.f, 0.f, 0.f, 0.f};
  }

  const int krow = lane >> 3, kcol = (lane & 7) * 8;   // K staging: 8 rows x 128B per chunk
  const int vrow = lane >> 4, vcol = (lane & 15) * 8;  // V staging: 4 rows x 256B per chunk
  ushort_t* Pw = Ps + wid * (32 * 128);

  for (int kt = 0; kt < 16; kt++) {
    __syncthreads();
#pragma unroll
    for (int c = 0; c < 4; c++) {
      const int ch = wid * 4 + c;
      GLD16(Kh  + base + (size_t)(kt * 128 + ch * 8 + krow) * DEPTH_ + kcol, Ks + ch * 512);
      GLD16(Vht + base + (size_t)(ch * 4 + vrow) * S_ + kt * 128 + vcol,     Vs + ch * 512);
    }
    __syncthreads();

    // S = Q K^T (scaled)
    f32x4 sa[2][8];
#pragma unroll
    for (int ni = 0; ni < 8; ni++) {
      u16x8 b0 = *(const u16x8*)(Ks + (ni * 16 + fr) * 64 + fq * 8);
      u16x8 b1 = *(const u16x8*)(Ks + (ni * 16 + fr) * 64 + 32 + fq * 8);
#pragma unroll
      for (int mi = 0; mi < 2; mi++) {
        f32x4 t = f32x4{0.f, 0.f, 0.f, 0.f};
        t = MFMA_BF16(qf[mi][0], b0, t);
        t = MFMA_BF16(qf[mi][1], b1, t);
        sa[mi][ni] = t;
      }
    }
    // mask: logits += mask * (-1e9); col of sa tile = key = kt*128 + ni*16 + fr
#pragma unroll
    for (int ni = 0; ni < 8; ni++) {
      const float mf = -1000000000.0f * (float)mask[b * S_ + kt * 128 + ni * 16 + fr];
#pragma unroll
      for (int mi = 0; mi < 2; mi++)
#pragma unroll
        for (int r = 0; r < 4; r++) sa[mi][ni][r] += mf;
    }
    // online softmax per q-row (row = wid*32 + mi*16 + fq*4 + r; 16 lanes share a row)
#pragma unroll
    for (int mi = 0; mi < 2; mi++) {
#pragma unroll
      for (int r = 0; r < 4; r++) {
        float rm = sa[mi][0][r];
#pragma unroll
        for (int ni = 1; ni < 8; ni++) rm = fmaxf(rm, sa[mi][ni][r]);
#pragma unroll
        for (int off = 1; off < 16; off <<= 1) rm = fmaxf(rm, __shfl_xor(rm, off, 64));
        const float mn = fmaxf(mstate[mi][r], rm);
        const float al = __expf(mstate[mi][r] - mn);
        mstate[mi][r] = mn;
        float rs = 0.f;
#pragma unroll
        for (int ni = 0; ni < 8; ni++) {
          float p = __expf(sa[mi][ni][r] - mn);
          sa[mi][ni][r] = p;
          rs += p;
        }
#pragma unroll
        for (int off = 1; off < 16; off <<= 1) rs += __shfl_xor(rs, off, 64);
        lstate[mi][r] = lstate[mi][r] * al + rs;
#pragma unroll
        for (int di = 0; di < 4; di++) O[mi][di][r] *= al;
      }
    }
    // P (C-layout) -> LDS bf16 (A-operand layout round-trip)
#pragma unroll
    for (int mi = 0; mi < 2; mi++)
#pragma unroll
      for (int ni = 0; ni < 8; ni++)
#pragma unroll
        for (int r = 0; r < 4; r++)
          Pw[(mi * 16 + fq * 4 + r) * 128 + ni * 16 + fr] = f2bf(sa[mi][ni][r]);
    __syncthreads();
    // O += P V
#pragma unroll
    for (int ks = 0; ks < 4; ks++) {
      u16x8 pa[2];
#pragma unroll
      for (int mi = 0; mi < 2; mi++) pa[mi] = *(const u16x8*)(Pw + (mi * 16 + fr) * 128 + ks * 32 + fq * 8);
#pragma unroll
      for (int di = 0; di < 4; di++) {
        u16x8 vb_ = *(const u16x8*)(Vs + (di * 16 + fr) * 128 + ks * 32 + fq * 8);
#pragma unroll
        for (int mi = 0; mi < 2; mi++) O[mi][di] = MFMA_BF16(pa[mi], vb_, O[mi][di]);
      }
    }
  }
  // epilogue: ctx[b][s][h*64+d] bf16
#pragma unroll
  for (int mi = 0; mi < 2; mi++)
#pragma unroll
    for (int r = 0; r < 4; r++) {
      const float inv = 1.f / lstate[mi][r];
      const int s = qt * 128 + wid * 32 + mi * 16 + fq * 4 + r;
#pragma unroll
      for (int di = 0; di < 4; di++) {
        const int col = h * DEPTH_ + di * 16 + fr;
        ctx[((size_t)(b * S_ + s)) * D_ + col] = f2bf(O[mi][di][r] * inv);
      }
    }
}

// ---------------- launch ----------------

extern "C" void kernel_launch(void* const* d_in, const int* in_sizes, int n_in,
                              void* d_out, int out_size, void* d_ws, size_t ws_size,
                              hipStream_t stream) {
  // setup_inputs order: v, k, q, mask, Wq, bq, Wk, bk, Wv, bv, Wo, bo
  const float* v  = (const float*)d_in[0];
  const float* k  = (const float*)d_in[1];
  const float* q  = (const float*)d_in[2];
  const int* mask = (const int*)d_in[3];
  const float* Wq = (const float*)d_in[4];
  const float* bq = (const float*)d_in[5];
  const float* Wk = (const float*)d_in[6];
  const float* bk = (const float*)d_in[7];
  const float* Wv = (const float*)d_in[8];
  const float* bv = (const float*)d_in[9];
  const float* Wo = (const float*)d_in[10];
  const float* bo = (const float*)d_in[11];
  float* out = (float*)d_out;

  char* ws = (char*)d_ws;
  ushort_t* qb  = (ushort_t*)(ws);
  ushort_t* kb  = (ushort_t*)(ws + (size_t)(16u << 20));
  ushort_t* vb  = (ushort_t*)(ws + (size_t)(32u << 20));
  ushort_t* Wqt = (ushort_t*)(ws + (size_t)(48u << 20));
  ushort_t* Wkt = (ushort_t*)(ws + (size_t)(50u << 20));
  ushort_t* Wvt = (ushort_t*)(ws + (size_t)(52u << 20));
  ushort_t* Wot = (ushort_t*)(ws + (size_t)(54u << 20));
  ushort_t* Qh  = (ushort_t*)(ws + (size_t)(56u << 20));
  ushort_t* Kh  = (ushort_t*)(ws + (size_t)(72u << 20));
  ushort_t* Vht = (ushort_t*)(ws + (size_t)(88u << 20));
  ushort_t* ctx = qb;  // qb dead after projections; alias as attention output

  cvt_acts_kernel<<<dim3(8192, 3), 256, 0, stream>>>(q, k, v, qb, kb, vb);
  cvt_wt_kernel<<<dim3(1024, 4), 256, 0, stream>>>(Wq, Wk, Wv, Wo, Wqt, Wkt, Wvt, Wot);
  qkv_gemm_kernel<<<dim3(8, 64, 3), 256, 0, stream>>>(qb, kb, vb, Wqt, Wkt, Wvt,
                                                      bq, bk, bv, Qh, Kh, Vht);
  attn_kernel<<<dim3(16, 64), 256, 0, stream>>>(Qh, Kh, Vht, mask, ctx);
  out_gemm_kernel<<<dim3(8, 64), 256, 0, stream>>>(ctx, Wot, bo, out);
}

// Round 2
// 354.311 us; speedup vs baseline: 1.5107x; 1.5107x over previous
//
#include <hip/hip_runtime.h>

// MultiHeadAttention B=4,S=2048,D=1024,H=16,depth=64.
// R2: S^T-orientation flash attention (no P round-trip), static-max exp2 softmax,
// MFMA ones-row l-sum, XOR-swizzled LDS, LDS-transposed sigma-permuted Vht epilogue.

typedef unsigned short ushort_t;
typedef __bf16          b16x8 __attribute__((ext_vector_type(8)));
typedef unsigned short  u16x8 __attribute__((ext_vector_type(8)));
typedef unsigned short  u16x4 __attribute__((ext_vector_type(4)));
typedef unsigned int    u32x4 __attribute__((ext_vector_type(4)));
typedef float           f32x4 __attribute__((ext_vector_type(4)));

#define B_ 4
#define S_ 2048
#define D_ 1024
#define H_ 16
#define DEPTH_ 64
#define LOG2E 1.4426950408889634f

__device__ __forceinline__ unsigned short f2bf(float f) {
  unsigned u = __builtin_bit_cast(unsigned, f);
  u += 0x7FFFu + ((u >> 16) & 1u);   // RTNE
  return (unsigned short)(u >> 16);
}

// pack two fp32 -> bf16x2 (truncation; P>=0 so bias is negligible and scale-invariant)
__device__ __forceinline__ unsigned pack_trunc(float lo, float hi) {
#if __has_builtin(__builtin_amdgcn_perm)
  return __builtin_amdgcn_perm(__builtin_bit_cast(unsigned, hi),
                               __builtin_bit_cast(unsigned, lo), 0x07060302u);
#else
  return (__builtin_bit_cast(unsigned, hi) & 0xFFFF0000u) |
         (__builtin_bit_cast(unsigned, lo) >> 16);
#endif
}

#if __has_builtin(__builtin_amdgcn_exp2f)
#define EXP2F(x) __builtin_amdgcn_exp2f(x)
#else
#define EXP2F(x) exp2f(x)
#endif

#define GLD16(gp, lp) __builtin_amdgcn_global_load_lds( \
    (__attribute__((address_space(1))) void*)(gp),       \
    (__attribute__((address_space(3))) void*)(lp), 16, 0, 0)

#define MFMA_BF16(a, b, c) __builtin_amdgcn_mfma_f32_16x16x32_bf16( \
    __builtin_bit_cast(b16x8, (a)), __builtin_bit_cast(b16x8, (b)), (c), 0, 0, 0)

// ---------------- converts ----------------

__global__ void cvt_acts_kernel(const float* __restrict__ q, const float* __restrict__ k,
                                const float* __restrict__ v,
                                ushort_t* __restrict__ qb, ushort_t* __restrict__ kb,
                                ushort_t* __restrict__ vb) {
  const float* src = blockIdx.y == 0 ? q : blockIdx.y == 1 ? k : v;
  ushort_t*    dst = blockIdx.y == 0 ? qb : blockIdx.y == 1 ? kb : vb;
  size_t i = ((size_t)blockIdx.x * 256 + threadIdx.x) * 4;
  float4 f = *(const float4*)(src + i);
  u16x4 o;
  o[0] = f2bf(f.x); o[1] = f2bf(f.y); o[2] = f2bf(f.z); o[3] = f2bf(f.w);
  *(u16x4*)(dst + i) = o;
}

__global__ void cvt_wt_kernel(const float* __restrict__ Wq, const float* __restrict__ Wk,
                              const float* __restrict__ Wv, const float* __restrict__ Wo,
                              ushort_t* __restrict__ Wqt, ushort_t* __restrict__ Wkt,
                              ushort_t* __restrict__ Wvt, ushort_t* __restrict__ Wot) {
  __shared__ float t[32][33];
  const int z = blockIdx.y;
  const float* W = z == 0 ? Wq : z == 1 ? Wk : z == 2 ? Wv : Wo;
  ushort_t*   Wt = z == 0 ? Wqt : z == 1 ? Wkt : z == 2 ? Wvt : Wot;
  const int x = threadIdx.x & 31, y0 = threadIdx.x >> 5;
  const int kt = (blockIdx.x & 31) * 32, nt = (blockIdx.x >> 5) * 32;
#pragma unroll
  for (int r = 0; r < 4; r++) {
    int row = y0 + r * 8;
    t[row][x] = W[(size_t)(kt + row) * D_ + nt + x];
  }
  __syncthreads();
#pragma unroll
  for (int r = 0; r < 4; r++) {
    int row = y0 + r * 8;
    Wt[(size_t)(nt + row) * D_ + kt + x] = f2bf(t[x][row]);
  }
}

// ---------------- GEMM core (m97 pattern + XOR bank swizzle) ----------------
// LDS tile: 128 rows x 32 u16. Physical 16B-chunk col = logical ^ ((row>>1)&3).

__device__ __forceinline__ void gemm_core(const ushort_t* __restrict__ A,
                                          const ushort_t* __restrict__ Bt,
                                          ushort_t* As, ushort_t* Bs,
                                          int tm, int tn, f32x4* acc) {
  const int tid = threadIdx.x;
  const int lane = tid & 63, wid = tid >> 6;
  const int wm = (wid >> 1) * 64, wn = (wid & 1) * 64;
  const int srow = lane >> 2;
  const int scolL = ((lane & 3) ^ ((srow >> 1) & 3)) * 8;   // swizzled logical col
  const int c0 = wid * 2, c1 = c0 + 1;
  const ushort_t* ga0 = A  + (size_t)(tm + c0 * 16 + srow) * D_ + scolL;
  const ushort_t* ga1 = A  + (size_t)(tm + c1 * 16 + srow) * D_ + scolL;
  const ushort_t* gb0 = Bt + (size_t)(tn + c0 * 16 + srow) * D_ + scolL;
  const ushort_t* gb1 = Bt + (size_t)(tn + c1 * 16 + srow) * D_ + scolL;
  ushort_t* lA0 = As + c0 * 512; ushort_t* lA1 = As + c1 * 512;
  ushort_t* lB0 = Bs + c0 * 512; ushort_t* lB1 = Bs + c1 * 512;
  const int fr = lane & 15;
  const int fswz = ((lane >> 4) ^ ((fr >> 1) & 3)) * 8;     // swizzled frag col offset
#pragma unroll
  for (int i = 0; i < 16; i++) acc[i] = f32x4{0.f, 0.f, 0.f, 0.f};
  for (int k0 = 0; k0 < D_; k0 += 32) {
    __syncthreads();
    GLD16(ga0 + k0, lA0);
    GLD16(ga1 + k0, lA1);
    GLD16(gb0 + k0, lB0);
    GLD16(gb1 + k0, lB1);
    __syncthreads();
    u16x8 af[4], bf[4];
#pragma unroll
    for (int mi = 0; mi < 4; mi++) af[mi] = *(const u16x8*)(As + (wm + mi * 16 + fr) * 32 + fswz);
#pragma unroll
    for (int ni = 0; ni < 4; ni++) bf[ni] = *(const u16x8*)(Bs + (wn + ni * 16 + fr) * 32 + fswz);
#pragma unroll
    for (int mi = 0; mi < 4; mi++)
#pragma unroll
      for (int ni = 0; ni < 4; ni++)
        acc[mi * 4 + ni] = MFMA_BF16(af[mi], bf[ni], acc[mi * 4 + ni]);
  }
}

// sigma permutation of keys within a 32-block (PV k-slot order)
__device__ __forceinline__ int sigma32(int k5) {
  return ((k5 & 15) >> 2) * 8 + ((k5 >> 4) & 1) * 4 + (k5 & 3);
}

// z=0: Q*log2e/8 -> Qh [B,H,S,64]; z=1: K -> Kh [B,H,S,64]; z=2: V -> Vht [B,H,64,S~sigma]
__global__ __launch_bounds__(256, 2) void qkv_gemm_kernel(
    const ushort_t* __restrict__ qb, const ushort_t* __restrict__ kb, const ushort_t* __restrict__ vb,
    const ushort_t* __restrict__ Wqt, const ushort_t* __restrict__ Wkt, const ushort_t* __restrict__ Wvt,
    const float* __restrict__ bq, const float* __restrict__ bk, const float* __restrict__ bv,
    ushort_t* __restrict__ Qh, ushort_t* __restrict__ Kh, ushort_t* __restrict__ Vht) {
  __shared__ __align__(16) ushort_t smem[128 * 136];   // As|Bs (8K u16) re-used as trans
  ushort_t* As = smem;
  ushort_t* Bs = smem + 4096;
  const int z = blockIdx.z;
  const ushort_t* A  = z == 0 ? qb : z == 1 ? kb : vb;
  const ushort_t* Bt = z == 0 ? Wqt : z == 1 ? Wkt : Wvt;
  const float* bias  = z == 0 ? bq : z == 1 ? bk : bv;
  const int tn = blockIdx.x * 128, tm = blockIdx.y * 128;
  f32x4 acc[16];
  gemm_core(A, Bt, As, Bs, tm, tn, acc);
  const int lane = threadIdx.x & 63, wid = threadIdx.x >> 6;
  const int wm = (wid >> 1) * 64, wn = (wid & 1) * 64;
  const int fr = lane & 15, rq = (lane >> 4) * 4;
  if (z == 2) {
    __syncthreads();                 // all waves done with As/Bs
    ushort_t* trans = smem;          // 128 x 136 u16
#pragma unroll
    for (int ni = 0; ni < 4; ni++) {
      const int n = wn + ni * 16 + fr;
      const float bb = bias[tn + n];
#pragma unroll
      for (int mi = 0; mi < 4; mi++) {
#pragma unroll
        for (int r = 0; r < 4; r++) {
          const int m = wm + mi * 16 + rq + r;
          const int mp = (m & ~31) + sigma32(m & 31);
          trans[n * 136 + mp] = f2bf(acc[mi * 4 + ni][r] + bb);
        }
      }
    }
    __syncthreads();
    const int n = threadIdx.x >> 1, hf = threadIdx.x & 1;
    const int col = tn + n, hh = col >> 6, dd = col & 63;
    const int bI = tm >> 11, sb = (tm & 2047) + hf * 64;
    ushort_t* dst = Vht + ((size_t)(bI * H_ + hh) * DEPTH_ + dd) * S_ + sb;
    const ushort_t* srcp = trans + n * 136 + hf * 64;
#pragma unroll
    for (int i = 0; i < 8; i++)
      *(u16x8*)(dst + i * 8) = *(const u16x8*)(srcp + i * 8);
  } else {
    ushort_t* outp = (z == 0) ? Qh : Kh;
    const float qscale = (z == 0) ? 0.125f * LOG2E : 1.0f;
#pragma unroll
    for (int ni = 0; ni < 4; ni++) {
      const int col = tn + wn + ni * 16 + fr;
      const float bb = bias[col];
      const int h = col >> 6, dd = col & 63;
#pragma unroll
      for (int mi = 0; mi < 4; mi++) {
#pragma unroll
        for (int r = 0; r < 4; r++) {
          const int m = tm + wm + mi * 16 + rq + r;
          const int b = m >> 11, s = m & 2047;
          outp[((size_t)(b * H_ + h) * S_ + s) * DEPTH_ + dd] =
              f2bf((acc[mi * 4 + ni][r] + bb) * qscale);
        }
      }
    }
  }
}

__global__ __launch_bounds__(256, 2) void out_gemm_kernel(
    const ushort_t* __restrict__ ctx, const ushort_t* __restrict__ Wot,
    const float* __restrict__ bo, float* __restrict__ out) {
  __shared__ __align__(16) ushort_t As[4096], Bs[4096];
  const int tn = blockIdx.x * 128, tm = blockIdx.y * 128;
  f32x4 acc[16];
  gemm_core(ctx, Wot, As, Bs, tm, tn, acc);
  const int lane = threadIdx.x & 63, wid = threadIdx.x >> 6;
  const int wm = (wid >> 1) * 64, wn = (wid & 1) * 64;
  const int fr = lane & 15, rq = (lane >> 4) * 4;
#pragma unroll
  for (int ni = 0; ni < 4; ni++) {
    const int col = tn + wn + ni * 16 + fr;
    const float bb = bo[col];
#pragma unroll
    for (int mi = 0; mi < 4; mi++) {
#pragma unroll
      for (int r = 0; r < 4; r++) {
        const int m = tm + wm + mi * 16 + rq + r;
        out[(size_t)m * D_ + col] = acc[mi * 4 + ni][r] + bb;
      }
    }
  }
}

// ---------------- flash attention, S^T orientation ----------------
// grid (16 q-tiles, 64 bh). 4 waves x 32 q rows. K tile 128 keys.
// S^T = K.Q^T : C-layout col=q(lane&15), row=key(quad*4+r)  ->  P^T feeds PV B-operand
// straight from registers (k-slot order sigma baked into Vht).

__global__ __launch_bounds__(256, 4) void attn_kernel(
    const ushort_t* __restrict__ Qh, const ushort_t* __restrict__ Kh,
    const ushort_t* __restrict__ Vht, const int* __restrict__ mask,
    ushort_t* __restrict__ ctx) {
  __shared__ __align__(16) ushort_t Ks[128 * 64];   // [key][d], 16B chunks ^ (row&7)
  __shared__ __align__(16) ushort_t Vs[64 * 128];   // [d][key-sigma], chunks ^ (row&15)
  __shared__ __align__(16) float Cm[2048];          // additive mask in log2 domain
  const int tid = threadIdx.x, lane = tid & 63, wid = tid >> 6;
  const int qt = blockIdx.x, bh = blockIdx.y;
  const int b = bh >> 4, h = bh & 15;
  const size_t base = (size_t)bh * (S_ * DEPTH_);
  const int fr = lane & 15, fq = lane >> 4;

  const int* mrow = mask + b * S_;
#pragma unroll
  for (int i = 0; i < 8; i++) {
    const int idx = tid + i * 256;
    Cm[idx] = mrow[idx] ? -1.4427e9f : 0.0f;
  }

  // Q fragments (B-operand; log2e/8 pre-folded at projection)
  u16x8 qf[2][2];
#pragma unroll
  for (int nq = 0; nq < 2; nq++)
#pragma unroll
    for (int kc = 0; kc < 2; kc++)
      qf[nq][kc] = *(const u16x8*)(Qh + base +
          (size_t)(qt * 128 + wid * 32 + nq * 16 + fr) * DEPTH_ + kc * 32 + fq * 8);

  // ones A-fragment (row 0 of a 16-row tile = 1.0bf16) for l = sum(p) via MFMA
  u16x8 ones_f;
  {
    const unsigned short o = (fr == 0) ? (unsigned short)0x3F80 : (unsigned short)0;
#pragma unroll
    for (int j = 0; j < 8; j++) ones_f[j] = o;
  }

  f32x4 Oa[4][2];
  f32x4 lacc[2];
#pragma unroll
  for (int di = 0; di < 4; di++)
#pragma unroll
    for (int nq = 0; nq < 2; nq++) Oa[di][nq] = f32x4{0.f, 0.f, 0.f, 0.f};
#pragma unroll
  for (int nq = 0; nq < 2; nq++) lacc[nq] = f32x4{0.f, 0.f, 0.f, 0.f};

  // staging lane->global swizzles
  const int krow = lane >> 3;                                   // K: 8 rows/chunk
  const int kcolL = ((lane & 7) ^ (krow & 7)) * 8;
  const int vrowc = lane >> 4;                                  // V: 4 rows/chunk
  // fragment-read swizzled offsets
  const int koff0 = ((0 + fq) ^ (fr & 7)) * 8;
  const int koff1 = ((4 + fq) ^ (fr & 7)) * 8;

  for (int kt = 0; kt < 16; kt++) {
    __syncthreads();
#pragma unroll
    for (int c = 0; c < 4; c++) {
      const int ch = wid * 4 + c;
      GLD16(Kh + base + (size_t)(kt * 128 + ch * 8 + krow) * DEPTH_ + kcolL, Ks + ch * 512);
      const int vrow = ch * 4 + vrowc;
      const int vcolL = ((lane & 15) ^ (vrow & 15)) * 8;
      GLD16(Vht + base + (size_t)vrow * S_ + kt * 128 + vcolL, Vs + ch * 512);
    }
    __syncthreads();

#pragma unroll
    for (int ks = 0; ks < 4; ks++) {
      const int nk0 = ks * 2, nk1 = nk0 + 1;
      const ushort_t* kr0 = Ks + (nk0 * 16 + fr) * 64;
      const ushort_t* kr1 = Ks + (nk1 * 16 + fr) * 64;
      const u16x8 a00 = *(const u16x8*)(kr0 + koff0);
      const u16x8 a01 = *(const u16x8*)(kr0 + koff1);
      const u16x8 a10 = *(const u16x8*)(kr1 + koff0);
      const u16x8 a11 = *(const u16x8*)(kr1 + koff1);
      f32x4 st0[2], st1[2];
#pragma unroll
      for (int nq = 0; nq < 2; nq++) {
        f32x4 t = f32x4{0.f, 0.f, 0.f, 0.f};
        t = MFMA_BF16(a00, qf[nq][0], t);
        t = MFMA_BF16(a01, qf[nq][1], t);
        st0[nq] = t;
        f32x4 u = f32x4{0.f, 0.f, 0.f, 0.f};
        u = MFMA_BF16(a10, qf[nq][0], u);
        u = MFMA_BF16(a11, qf[nq][1], u);
        st1[nq] = u;
      }
      const f32x4 cm0 = *(const f32x4*)(Cm + kt * 128 + nk0 * 16 + fq * 4);
      const f32x4 cm1 = *(const f32x4*)(Cm + kt * 128 + nk1 * 16 + fq * 4);
      u16x8 pb[2];
#pragma unroll
      for (int nq = 0; nq < 2; nq++) {
#pragma unroll
        for (int r = 0; r < 4; r++) {
          st0[nq][r] = EXP2F(st0[nq][r] + cm0[r]);
          st1[nq][r] = EXP2F(st1[nq][r] + cm1[r]);
        }
        u32x4 pk;
        pk[0] = pack_trunc(st0[nq][0], st0[nq][1]);
        pk[1] = pack_trunc(st0[nq][2], st0[nq][3]);
        pk[2] = pack_trunc(st1[nq][0], st1[nq][1]);
        pk[3] = pack_trunc(st1[nq][2], st1[nq][3]);
        pb[nq] = __builtin_bit_cast(u16x8, pk);
      }
      const int voff = ((ks * 4 + fq) ^ fr) * 8;
#pragma unroll
      for (int di = 0; di < 4; di++) {
        const u16x8 vf = *(const u16x8*)(Vs + (di * 16 + fr) * 128 + voff);
#pragma unroll
        for (int nq = 0; nq < 2; nq++)
          Oa[di][nq] = MFMA_BF16(vf, pb[nq], Oa[di][nq]);
      }
#pragma unroll
      for (int nq = 0; nq < 2; nq++)
        lacc[nq] = MFMA_BF16(ones_f, pb[nq], lacc[nq]);
    }
  }

  // epilogue: O^T C-layout: col=q=fr, row=d=di*16+fq*4+r. l lives on lanes 0..15 (reg 0).
#pragma unroll
  for (int nq = 0; nq < 2; nq++) {
    const int lv = __builtin_amdgcn_ds_bpermute(fr * 4, __builtin_bit_cast(int, lacc[nq][0]));
    const float inv = 1.0f / __builtin_bit_cast(float, lv);
    const int sg = qt * 128 + wid * 32 + nq * 16 + fr;
    ushort_t* crow = ctx + ((size_t)(b * S_ + sg)) * D_ + h * DEPTH_;
#pragma unroll
    for (int di = 0; di < 4; di++) {
      u16x4 o4;
#pragma unroll
      for (int r = 0; r < 4; r++) o4[r] = f2bf(Oa[di][nq][r] * inv);
      *(u16x4*)(crow + di * 16 + fq * 4) = o4;
    }
  }
}

// ---------------- launch ----------------

extern "C" void kernel_launch(void* const* d_in, const int* in_sizes, int n_in,
                              void* d_out, int out_size, void* d_ws, size_t ws_size,
                              hipStream_t stream) {
  const float* v  = (const float*)d_in[0];
  const float* k  = (const float*)d_in[1];
  const float* q  = (const float*)d_in[2];
  const int* mask = (const int*)d_in[3];
  const float* Wq = (const float*)d_in[4];
  const float* bq = (const float*)d_in[5];
  const float* Wk = (const float*)d_in[6];
  const float* bk = (const float*)d_in[7];
  const float* Wv = (const float*)d_in[8];
  const float* bv = (const float*)d_in[9];
  const float* Wo = (const float*)d_in[10];
  const float* bo = (const float*)d_in[11];
  float* out = (float*)d_out;

  char* ws = (char*)d_ws;
  ushort_t* qb  = (ushort_t*)(ws);
  ushort_t* kb  = (ushort_t*)(ws + (size_t)(16u << 20));
  ushort_t* vb  = (ushort_t*)(ws + (size_t)(32u << 20));
  ushort_t* Wqt = (ushort_t*)(ws + (size_t)(48u << 20));
  ushort_t* Wkt = (ushort_t*)(ws + (size_t)(50u << 20));
  ushort_t* Wvt = (ushort_t*)(ws + (size_t)(52u << 20));
  ushort_t* Wot = (ushort_t*)(ws + (size_t)(54u << 20));
  ushort_t* Qh  = (ushort_t*)(ws + (size_t)(56u << 20));
  ushort_t* Kh  = (ushort_t*)(ws + (size_t)(72u << 20));
  ushort_t* Vht = (ushort_t*)(ws + (size_t)(88u << 20));
  ushort_t* ctx = qb;  // qb dead after projections

  cvt_acts_kernel<<<dim3(8192, 3), 256, 0, stream>>>(q, k, v, qb, kb, vb);
  cvt_wt_kernel<<<dim3(1024, 4), 256, 0, stream>>>(Wq, Wk, Wv, Wo, Wqt, Wkt, Wvt, Wot);
  qkv_gemm_kernel<<<dim3(8, 64, 3), 256, 0, stream>>>(qb, kb, vb, Wqt, Wkt, Wvt,
                                                      bq, bk, bv, Qh, Kh, Vht);
  attn_kernel<<<dim3(16, 64), 256, 0, stream>>>(Qh, Kh, Vht, mask, ctx);
  out_gemm_kernel<<<dim3(8, 64), 256, 0, stream>>>(ctx, Wot, bo, out);
}

// Round 3
// 323.702 us; speedup vs baseline: 1.6536x; 1.0946x over previous
//
#include <hip/hip_runtime.h>

// MultiHeadAttention B=4,S=2048,D=1024,H=16,depth=64.
// R3: XCD-aware block swizzle (L2 locality), BK=64 GEMM core (half the barrier
// drains), sequential k-half fragments to bound VGPR. Attention unchanged except
// XCD swizzle.

typedef unsigned short ushort_t;
typedef __bf16          b16x8 __attribute__((ext_vector_type(8)));
typedef unsigned short  u16x8 __attribute__((ext_vector_type(8)));
typedef unsigned short  u16x4 __attribute__((ext_vector_type(4)));
typedef unsigned int    u32x4 __attribute__((ext_vector_type(4)));
typedef float           f32x4 __attribute__((ext_vector_type(4)));

#define B_ 4
#define S_ 2048
#define D_ 1024
#define H_ 16
#define DEPTH_ 64
#define LOG2E 1.4426950408889634f

__device__ __forceinline__ unsigned short f2bf(float f) {
  unsigned u = __builtin_bit_cast(unsigned, f);
  u += 0x7FFFu + ((u >> 16) & 1u);   // RTNE
  return (unsigned short)(u >> 16);
}

__device__ __forceinline__ unsigned pack_trunc(float lo, float hi) {
#if __has_builtin(__builtin_amdgcn_perm)
  return __builtin_amdgcn_perm(__builtin_bit_cast(unsigned, hi),
                               __builtin_bit_cast(unsigned, lo), 0x07060302u);
#else
  return (__builtin_bit_cast(unsigned, hi) & 0xFFFF0000u) |
         (__builtin_bit_cast(unsigned, lo) >> 16);
#endif
}

#if __has_builtin(__builtin_amdgcn_exp2f)
#define EXP2F(x) __builtin_amdgcn_exp2f(x)
#else
#define EXP2F(x) exp2f(x)
#endif

#define GLD16(gp, lp) __builtin_amdgcn_global_load_lds( \
    (__attribute__((address_space(1))) void*)(gp),       \
    (__attribute__((address_space(3))) void*)(lp), 16, 0, 0)

#define MFMA_BF16(a, b, c) __builtin_amdgcn_mfma_f32_16x16x32_bf16( \
    __builtin_bit_cast(b16x8, (a)), __builtin_bit_cast(b16x8, (b)), (c), 0, 0, 0)

// ---------------- converts ----------------

__global__ void cvt_acts_kernel(const float* __restrict__ q, const float* __restrict__ k,
                                const float* __restrict__ v,
                                ushort_t* __restrict__ qb, ushort_t* __restrict__ kb,
                                ushort_t* __restrict__ vb) {
  const float* src = blockIdx.y == 0 ? q : blockIdx.y == 1 ? k : v;
  ushort_t*    dst = blockIdx.y == 0 ? qb : blockIdx.y == 1 ? kb : vb;
  size_t i = ((size_t)blockIdx.x * 256 + threadIdx.x) * 4;
  float4 f = *(const float4*)(src + i);
  u16x4 o;
  o[0] = f2bf(f.x); o[1] = f2bf(f.y); o[2] = f2bf(f.z); o[3] = f2bf(f.w);
  *(u16x4*)(dst + i) = o;
}

__global__ void cvt_wt_kernel(const float* __restrict__ Wq, const float* __restrict__ Wk,
                              const float* __restrict__ Wv, const float* __restrict__ Wo,
                              ushort_t* __restrict__ Wqt, ushort_t* __restrict__ Wkt,
                              ushort_t* __restrict__ Wvt, ushort_t* __restrict__ Wot) {
  __shared__ float t[32][33];
  const int z = blockIdx.y;
  const float* W = z == 0 ? Wq : z == 1 ? Wk : z == 2 ? Wv : Wo;
  ushort_t*   Wt = z == 0 ? Wqt : z == 1 ? Wkt : z == 2 ? Wvt : Wot;
  const int x = threadIdx.x & 31, y0 = threadIdx.x >> 5;
  const int kt = (blockIdx.x & 31) * 32, nt = (blockIdx.x >> 5) * 32;
#pragma unroll
  for (int r = 0; r < 4; r++) {
    int row = y0 + r * 8;
    t[row][x] = W[(size_t)(kt + row) * D_ + nt + x];
  }
  __syncthreads();
#pragma unroll
  for (int r = 0; r < 4; r++) {
    int row = y0 + r * 8;
    Wt[(size_t)(nt + row) * D_ + kt + x] = f2bf(t[x][row]);
  }
}

// ---------------- GEMM core: 128x128 tile, BK=64, XOR-swizzled LDS ----------------
// LDS tile 128 rows x 64 u16 (128B row = 8 x 16B chunks). Physical chunk =
// logical ^ (row&7). Staging GLD16: lane l of instr ch covers row ch*8+(l>>3),
// phys chunk l&7 -> logical (l&7)^(l>>3). Fragment reads 2-way-bank max (free).

__device__ __forceinline__ void gemm_core(const ushort_t* __restrict__ A,
                                          const ushort_t* __restrict__ Bt,
                                          ushort_t* As, ushort_t* Bs,
                                          int tm, int tn, f32x4* acc) {
  const int tid = threadIdx.x;
  const int lane = tid & 63, wid = tid >> 6;
  const int wm = (wid >> 1) * 64, wn = (wid & 1) * 64;
  const int srow = lane >> 3;
  const int scol = ((lane & 7) ^ srow) * 8;     // swizzled source k-offset (u16)
  const ushort_t* gA[4];
  const ushort_t* gB[4];
#pragma unroll
  for (int c = 0; c < 4; c++) {
    const int ch = wid * 4 + c;                 // 8-row chunk id 0..15
    gA[c] = A  + (size_t)(tm + ch * 8 + srow) * D_ + scol;
    gB[c] = Bt + (size_t)(tn + ch * 8 + srow) * D_ + scol;
  }
  const int fr = lane & 15, fq = lane >> 4;
#pragma unroll
  for (int i = 0; i < 16; i++) acc[i] = f32x4{0.f, 0.f, 0.f, 0.f};
  for (int k0 = 0; k0 < D_; k0 += 64) {
    __syncthreads();
#pragma unroll
    for (int c = 0; c < 4; c++) {
      const int ch = wid * 4 + c;
      GLD16(gA[c] + k0, As + ch * 512);
      GLD16(gB[c] + k0, Bs + ch * 512);
    }
    __syncthreads();
#pragma unroll
    for (int kh = 0; kh < 2; kh++) {
      const int coff = (((kh * 4 + fq) ^ (fr & 7))) * 8;
      u16x8 af[4], bf[4];
#pragma unroll
      for (int mi = 0; mi < 4; mi++)
        af[mi] = *(const u16x8*)(As + (wm + mi * 16 + fr) * 64 + coff);
#pragma unroll
      for (int ni = 0; ni < 4; ni++)
        bf[ni] = *(const u16x8*)(Bs + (wn + ni * 16 + fr) * 64 + coff);
#pragma unroll
      for (int mi = 0; mi < 4; mi++)
#pragma unroll
        for (int ni = 0; ni < 4; ni++)
          acc[mi * 4 + ni] = MFMA_BF16(af[mi], bf[ni], acc[mi * 4 + ni]);
    }
  }
}

// sigma permutation of keys within a 32-block (PV k-slot order)
__device__ __forceinline__ int sigma32(int k5) {
  return ((k5 & 15) >> 2) * 8 + ((k5 >> 4) & 1) * 4 + (k5 & 3);
}

// XCD swizzle: linear bx -> (tm,tn) s.t. all 8 tn of one tm are consecutive on
// one XCD (assumes round-robin block->XCD by linear id % 8).
__device__ __forceinline__ void gemm_tile_swizzle(int bx, int& tm, int& tn) {
  const int xcd = bx & 7, j = bx >> 3;
  tn = (j & 7) * 128;
  tm = (((j >> 3) << 3) | xcd) * 128;
}

// z=0: Q*log2e/8 -> Qh [B,H,S,64]; z=1: K -> Kh; z=2: V -> Vht [B,H,64,S~sigma]
__global__ __launch_bounds__(256, 3) void qkv_gemm_kernel(
    const ushort_t* __restrict__ qb, const ushort_t* __restrict__ kb, const ushort_t* __restrict__ vb,
    const ushort_t* __restrict__ Wqt, const ushort_t* __restrict__ Wkt, const ushort_t* __restrict__ Wvt,
    const float* __restrict__ bq, const float* __restrict__ bk, const float* __restrict__ bv,
    ushort_t* __restrict__ Qh, ushort_t* __restrict__ Kh, ushort_t* __restrict__ Vht) {
  __shared__ __align__(16) ushort_t smem[128 * 136];   // As(8K u16)|Bs(8K u16); trans overlay
  ushort_t* As = smem;
  ushort_t* Bs = smem + 8192;
  const int z = blockIdx.z;
  const ushort_t* A  = z == 0 ? qb : z == 1 ? kb : vb;
  const ushort_t* Bt = z == 0 ? Wqt : z == 1 ? Wkt : Wvt;
  const float* bias  = z == 0 ? bq : z == 1 ? bk : bv;
  int tm, tn;
  gemm_tile_swizzle(blockIdx.x, tm, tn);
  f32x4 acc[16];
  gemm_core(A, Bt, As, Bs, tm, tn, acc);
  const int lane = threadIdx.x & 63, wid = threadIdx.x >> 6;
  const int wm = (wid >> 1) * 64, wn = (wid & 1) * 64;
  const int fr = lane & 15, rq = (lane >> 4) * 4;
  if (z == 2) {
    __syncthreads();                 // all waves done with As/Bs
    ushort_t* trans = smem;          // 128 x 136 u16
#pragma unroll
    for (int ni = 0; ni < 4; ni++) {
      const int n = wn + ni * 16 + fr;
      const float bb = bias[tn + n];
#pragma unroll
      for (int mi = 0; mi < 4; mi++) {
#pragma unroll
        for (int r = 0; r < 4; r++) {
          const int m = wm + mi * 16 + rq + r;
          const int mp = (m & ~31) + sigma32(m & 31);
          trans[n * 136 + mp] = f2bf(acc[mi * 4 + ni][r] + bb);
        }
      }
    }
    __syncthreads();
    const int n = threadIdx.x >> 1, hf = threadIdx.x & 1;
    const int col = tn + n, hh = col >> 6, dd = col & 63;
    const int bI = tm >> 11, sb = (tm & 2047) + hf * 64;
    ushort_t* dst = Vht + ((size_t)(bI * H_ + hh) * DEPTH_ + dd) * S_ + sb;
    const ushort_t* srcp = trans + n * 136 + hf * 64;
#pragma unroll
    for (int i = 0; i < 8; i++)
      *(u16x8*)(dst + i * 8) = *(const u16x8*)(srcp + i * 8);
  } else {
    ushort_t* outp = (z == 0) ? Qh : Kh;
    const float qscale = (z == 0) ? 0.125f * LOG2E : 1.0f;
#pragma unroll
    for (int ni = 0; ni < 4; ni++) {
      const int col = tn + wn + ni * 16 + fr;
      const float bb = bias[col];
      const int h = col >> 6, dd = col & 63;
#pragma unroll
      for (int mi = 0; mi < 4; mi++) {
#pragma unroll
        for (int r = 0; r < 4; r++) {
          const int m = tm + wm + mi * 16 + rq + r;
          const int b = m >> 11, s = m & 2047;
          outp[((size_t)(b * H_ + h) * S_ + s) * DEPTH_ + dd] =
              f2bf((acc[mi * 4 + ni][r] + bb) * qscale);
        }
      }
    }
  }
}

__global__ __launch_bounds__(256, 3) void out_gemm_kernel(
    const ushort_t* __restrict__ ctx, const ushort_t* __restrict__ Wot,
    const float* __restrict__ bo, float* __restrict__ out) {
  __shared__ __align__(16) ushort_t As[8192], Bs[8192];
  int tm, tn;
  gemm_tile_swizzle(blockIdx.x, tm, tn);
  f32x4 acc[16];
  gemm_core(ctx, Wot, As, Bs, tm, tn, acc);
  const int lane = threadIdx.x & 63, wid = threadIdx.x >> 6;
  const int wm = (wid >> 1) * 64, wn = (wid & 1) * 64;
  const int fr = lane & 15, rq = (lane >> 4) * 4;
#pragma unroll
  for (int ni = 0; ni < 4; ni++) {
    const int col = tn + wn + ni * 16 + fr;
    const float bb = bo[col];
#pragma unroll
    for (int mi = 0; mi < 4; mi++) {
#pragma unroll
      for (int r = 0; r < 4; r++) {
        const int m = tm + wm + mi * 16 + rq + r;
        out[(size_t)m * D_ + col] = acc[mi * 4 + ni][r] + bb;
      }
    }
  }
}

// ---------------- flash attention, S^T orientation ----------------

__global__ __launch_bounds__(256, 4) void attn_kernel(
    const ushort_t* __restrict__ Qh, const ushort_t* __restrict__ Kh,
    const ushort_t* __restrict__ Vht, const int* __restrict__ mask,
    ushort_t* __restrict__ ctx) {
  __shared__ __align__(16) ushort_t Ks[128 * 64];   // [key][d], chunks ^ (row&7)
  __shared__ __align__(16) ushort_t Vs[64 * 128];   // [d][key-sigma], chunks ^ (row&15)
  __shared__ __align__(16) float Cm[2048];          // additive mask, log2 domain
  const int tid = threadIdx.x, lane = tid & 63, wid = tid >> 6;
  // XCD swizzle: all 16 q-tiles of one bh consecutive on one XCD
  const int id = blockIdx.x;
  const int xcd = id & 7, j = id >> 3;
  const int qt = j & 15;
  const int bh = xcd * 8 + (j >> 4);
  const int b = bh >> 4, h = bh & 15;
  const size_t base = (size_t)bh * (S_ * DEPTH_);
  const int fr = lane & 15, fq = lane >> 4;

  const int* mrow = mask + b * S_;
#pragma unroll
  for (int i = 0; i < 8; i++) {
    const int idx = tid + i * 256;
    Cm[idx] = mrow[idx] ? -1.4427e9f : 0.0f;
  }

  u16x8 qf[2][2];
#pragma unroll
  for (int nq = 0; nq < 2; nq++)
#pragma unroll
    for (int kc = 0; kc < 2; kc++)
      qf[nq][kc] = *(const u16x8*)(Qh + base +
          (size_t)(qt * 128 + wid * 32 + nq * 16 + fr) * DEPTH_ + kc * 32 + fq * 8);

  u16x8 ones_f;
  {
    const unsigned short o = (fr == 0) ? (unsigned short)0x3F80 : (unsigned short)0;
#pragma unroll
    for (int jj = 0; jj < 8; jj++) ones_f[jj] = o;
  }

  f32x4 Oa[4][2];
  f32x4 lacc[2];
#pragma unroll
  for (int di = 0; di < 4; di++)
#pragma unroll
    for (int nq = 0; nq < 2; nq++) Oa[di][nq] = f32x4{0.f, 0.f, 0.f, 0.f};
#pragma unroll
  for (int nq = 0; nq < 2; nq++) lacc[nq] = f32x4{0.f, 0.f, 0.f, 0.f};

  const int krow = lane >> 3;
  const int kcolL = ((lane & 7) ^ (krow & 7)) * 8;
  const int vrowc = lane >> 4;
  const int koff0 = ((0 + fq) ^ (fr & 7)) * 8;
  const int koff1 = ((4 + fq) ^ (fr & 7)) * 8;

  for (int kt = 0; kt < 16; kt++) {
    __syncthreads();
#pragma unroll
    for (int c = 0; c < 4; c++) {
      const int ch = wid * 4 + c;
      GLD16(Kh + base + (size_t)(kt * 128 + ch * 8 + krow) * DEPTH_ + kcolL, Ks + ch * 512);
      const int vrow = ch * 4 + vrowc;
      const int vcolL = ((lane & 15) ^ (vrow & 15)) * 8;
      GLD16(Vht + base + (size_t)vrow * S_ + kt * 128 + vcolL, Vs + ch * 512);
    }
    __syncthreads();

#pragma unroll
    for (int ks = 0; ks < 4; ks++) {
      const int nk0 = ks * 2, nk1 = nk0 + 1;
      const ushort_t* kr0 = Ks + (nk0 * 16 + fr) * 64;
      const ushort_t* kr1 = Ks + (nk1 * 16 + fr) * 64;
      const u16x8 a00 = *(const u16x8*)(kr0 + koff0);
      const u16x8 a01 = *(const u16x8*)(kr0 + koff1);
      const u16x8 a10 = *(const u16x8*)(kr1 + koff0);
      const u16x8 a11 = *(const u16x8*)(kr1 + koff1);
      f32x4 st0[2], st1[2];
#pragma unroll
      for (int nq = 0; nq < 2; nq++) {
        f32x4 t = f32x4{0.f, 0.f, 0.f, 0.f};
        t = MFMA_BF16(a00, qf[nq][0], t);
        t = MFMA_BF16(a01, qf[nq][1], t);
        st0[nq] = t;
        f32x4 u = f32x4{0.f, 0.f, 0.f, 0.f};
        u = MFMA_BF16(a10, qf[nq][0], u);
        u = MFMA_BF16(a11, qf[nq][1], u);
        st1[nq] = u;
      }
      const f32x4 cm0 = *(const f32x4*)(Cm + kt * 128 + nk0 * 16 + fq * 4);
      const f32x4 cm1 = *(const f32x4*)(Cm + kt * 128 + nk1 * 16 + fq * 4);
      u16x8 pb[2];
#pragma unroll
      for (int nq = 0; nq < 2; nq++) {
#pragma unroll
        for (int r = 0; r < 4; r++) {
          st0[nq][r] = EXP2F(st0[nq][r] + cm0[r]);
          st1[nq][r] = EXP2F(st1[nq][r] + cm1[r]);
        }
        u32x4 pk;
        pk[0] = pack_trunc(st0[nq][0], st0[nq][1]);
        pk[1] = pack_trunc(st0[nq][2], st0[nq][3]);
        pk[2] = pack_trunc(st1[nq][0], st1[nq][1]);
        pk[3] = pack_trunc(st1[nq][2], st1[nq][3]);
        pb[nq] = __builtin_bit_cast(u16x8, pk);
      }
      const int voff = ((ks * 4 + fq) ^ fr) * 8;
#pragma unroll
      for (int di = 0; di < 4; di++) {
        const u16x8 vf = *(const u16x8*)(Vs + (di * 16 + fr) * 128 + voff);
#pragma unroll
        for (int nq = 0; nq < 2; nq++)
          Oa[di][nq] = MFMA_BF16(vf, pb[nq], Oa[di][nq]);
      }
#pragma unroll
      for (int nq = 0; nq < 2; nq++)
        lacc[nq] = MFMA_BF16(ones_f, pb[nq], lacc[nq]);
    }
  }

#pragma unroll
  for (int nq = 0; nq < 2; nq++) {
    const int lv = __builtin_amdgcn_ds_bpermute(fr * 4, __builtin_bit_cast(int, lacc[nq][0]));
    const float inv = 1.0f / __builtin_bit_cast(float, lv);
    const int sg = qt * 128 + wid * 32 + nq * 16 + fr;
    ushort_t* crow = ctx + ((size_t)(b * S_ + sg)) * D_ + h * DEPTH_;
#pragma unroll
    for (int di = 0; di < 4; di++) {
      u16x4 o4;
#pragma unroll
      for (int r = 0; r < 4; r++) o4[r] = f2bf(Oa[di][nq][r] * inv);
      *(u16x4*)(crow + di * 16 + fq * 4) = o4;
    }
  }
}

// ---------------- launch ----------------

extern "C" void kernel_launch(void* const* d_in, const int* in_sizes, int n_in,
                              void* d_out, int out_size, void* d_ws, size_t ws_size,
                              hipStream_t stream) {
  const float* v  = (const float*)d_in[0];
  const float* k  = (const float*)d_in[1];
  const float* q  = (const float*)d_in[2];
  const int* mask = (const int*)d_in[3];
  const float* Wq = (const float*)d_in[4];
  const float* bq = (const float*)d_in[5];
  const float* Wk = (const float*)d_in[6];
  const float* bk = (const float*)d_in[7];
  const float* Wv = (const float*)d_in[8];
  const float* bv = (const float*)d_in[9];
  const float* Wo = (const float*)d_in[10];
  const float* bo = (const float*)d_in[11];
  float* out = (float*)d_out;

  char* ws = (char*)d_ws;
  ushort_t* qb  = (ushort_t*)(ws);
  ushort_t* kb  = (ushort_t*)(ws + (size_t)(16u << 20));
  ushort_t* vb  = (ushort_t*)(ws + (size_t)(32u << 20));
  ushort_t* Wqt = (ushort_t*)(ws + (size_t)(48u << 20));
  ushort_t* Wkt = (ushort_t*)(ws + (size_t)(50u << 20));
  ushort_t* Wvt = (ushort_t*)(ws + (size_t)(52u << 20));
  ushort_t* Wot = (ushort_t*)(ws + (size_t)(54u << 20));
  ushort_t* Qh  = (ushort_t*)(ws + (size_t)(56u << 20));
  ushort_t* Kh  = (ushort_t*)(ws + (size_t)(72u << 20));
  ushort_t* Vht = (ushort_t*)(ws + (size_t)(88u << 20));
  ushort_t* ctx = qb;  // qb dead after projections

  cvt_acts_kernel<<<dim3(8192, 3), 256, 0, stream>>>(q, k, v, qb, kb, vb);
  cvt_wt_kernel<<<dim3(1024, 4), 256, 0, stream>>>(Wq, Wk, Wv, Wo, Wqt, Wkt, Wvt, Wot);
  qkv_gemm_kernel<<<dim3(512, 1, 3), 256, 0, stream>>>(qb, kb, vb, Wqt, Wkt, Wvt,
                                                       bq, bk, bv, Qh, Kh, Vht);
  attn_kernel<<<dim3(1024), 256, 0, stream>>>(Qh, Kh, Vht, mask, ctx);
  out_gemm_kernel<<<dim3(512), 256, 0, stream>>>(ctx, Wot, bo, out);
}